// Round 1
// baseline (2572.532 us; speedup 1.0000x reference)
//
#include <hip/hip_runtime.h>
#include <stdint.h>

#define N_TOK 4096
#define DIM_IN 512
#define NH 12
#define HD 64
#define CDIM 768   // NH*HD

using f32x4  = __attribute__((ext_vector_type(4))) float;
using bf16x8 = __attribute__((ext_vector_type(8))) short;

static __device__ __forceinline__ unsigned short f2bf(float f){
    union { float f; unsigned int u; } v; v.f = f;
    unsigned int r = v.u + 0x7fffu + ((v.u >> 16) & 1u);
    return (unsigned short)(r >> 16);
}

// ---------------------------------------------------------------------------
// proj: out[n][c] = (sum_d g[n][d]*W[c][d] + B[c]) * (scale ? scale[c/64] : 1)
// stored as bf16.  64x64 tile, BK=16, 256 threads, 4x4 micro.
// ---------------------------------------------------------------------------
__global__ __launch_bounds__(256) void proj_kernel(
    const float* __restrict__ g, const float* __restrict__ W,
    const float* __restrict__ B, const float* __restrict__ scale,
    unsigned short* __restrict__ out)
{
    __shared__ float at[16][68];
    __shared__ float bt[16][68];
    const int n0 = blockIdx.x * 64, c0 = blockIdx.y * 64;
    const int t  = threadIdx.x;
    const int tx = t & 15, ty = t >> 4;
    const int lr = t >> 2, lk = (t & 3) * 4;
    float acc[4][4] = {};
    for (int d0 = 0; d0 < DIM_IN; d0 += 16){
        __syncthreads();
        f32x4 gv = *(const f32x4*)&g[(size_t)(n0 + lr) * DIM_IN + d0 + lk];
        at[lk+0][lr] = gv[0]; at[lk+1][lr] = gv[1]; at[lk+2][lr] = gv[2]; at[lk+3][lr] = gv[3];
        f32x4 wv = *(const f32x4*)&W[(size_t)(c0 + lr) * DIM_IN + d0 + lk];
        bt[lk+0][lr] = wv[0]; bt[lk+1][lr] = wv[1]; bt[lk+2][lr] = wv[2]; bt[lk+3][lr] = wv[3];
        __syncthreads();
        #pragma unroll
        for (int kk = 0; kk < 16; kk++){
            f32x4 av = *(const f32x4*)&at[kk][ty*4];
            f32x4 bv = *(const f32x4*)&bt[kk][tx*4];
            #pragma unroll
            for (int i = 0; i < 4; i++)
                #pragma unroll
                for (int j = 0; j < 4; j++)
                    acc[i][j] += av[i] * bv[j];
        }
    }
    #pragma unroll
    for (int i = 0; i < 4; i++){
        const int n = n0 + ty*4 + i;
        #pragma unroll
        for (int j = 0; j < 4; j++){
            const int c = c0 + tx*4 + j;
            float v = acc[i][j] + B[c];
            if (scale) v *= scale[c >> 6];
            out[(size_t)n * CDIM + c] = f2bf(v);
        }
    }
}

// ---------------------------------------------------------------------------
// forward: per 16x16 (q,k) MFMA tile, 12 head scores -> Hw mix -> adj mask ->
// accumulate sum(exp) per (q-row, h').  atomicAdd partials into l_ws.
// block = 256 thr = 4 waves; each wave owns a 16-q tile (block covers 64 q).
// grid = (4096/64, KSF); each block walks a k segment in chunks of 32.
// ---------------------------------------------------------------------------
#define TKF 32
#define KBS 776   // ushort stride: 1552 B (16B aligned, 2-way-bank only)

__global__ __launch_bounds__(256, 2) void fwd_kernel(
    const unsigned short* __restrict__ Qb, const unsigned short* __restrict__ Kh,
    const float* __restrict__ adj, const float* __restrict__ HwG,
    float* __restrict__ l_ws, int seg_len)
{
    __shared__ unsigned short kbuf[TKF][KBS];
    __shared__ float hw[NH][12];
    const int t = threadIdx.x;
    if (t < NH * 12) hw[t / 12][t % 12] = HwG[t];
    const int lane = t & 63, wave = t >> 6;
    const int quad = lane >> 4, col = lane & 15;
    const int qt0 = blockIdx.x * 64 + wave * 16;
    const int kstart = blockIdx.y * seg_len;

    // A fragments (this wave's 16 q rows), persistent in registers
    bf16x8 af[NH][2];
    {
        const int arow = qt0 + col;   // A: m = lane&15
        #pragma unroll
        for (int h = 0; h < NH; h++)
            #pragma unroll
            for (int kk = 0; kk < 2; kk++)
                af[h][kk] = *(const bf16x8*)&Qb[(size_t)arow * CDIM + h*HD + kk*32 + quad*8];
    }
    f32x4 l4[4][3];
    #pragma unroll
    for (int r = 0; r < 4; r++)
        #pragma unroll
        for (int j = 0; j < 3; j++)
            l4[r][j] = (f32x4){0.f,0.f,0.f,0.f};

    for (int kc = kstart; kc < kstart + seg_len; kc += TKF){
        __syncthreads();
        #pragma unroll
        for (int i = 0; i < 12; i++){
            const int idx = t + 256 * i;
            const int row = idx / 96, cc = (idx % 96) * 8;
            *(bf16x8*)&kbuf[row][cc] = *(const bf16x8*)&Kh[(size_t)(kc + row) * CDIM + cc];
        }
        __syncthreads();
        #pragma unroll
        for (int sub = 0; sub < 2; sub++){
            const int k0 = kc + sub * 16;
            f32x4 tv[4][3];
            #pragma unroll
            for (int r = 0; r < 4; r++)
                #pragma unroll
                for (int j = 0; j < 3; j++)
                    tv[r][j] = (f32x4){0.f,0.f,0.f,0.f};
            #pragma unroll
            for (int h = 0; h < NH; h++){
                bf16x8 b0 = *(const bf16x8*)&kbuf[sub*16 + col][h*HD + quad*8];
                bf16x8 b1 = *(const bf16x8*)&kbuf[sub*16 + col][h*HD + 32 + quad*8];
                f32x4 s = {0.f,0.f,0.f,0.f};
                s = __builtin_amdgcn_mfma_f32_16x16x32_bf16(af[h][0], b0, s, 0, 0, 0);
                s = __builtin_amdgcn_mfma_f32_16x16x32_bf16(af[h][1], b1, s, 0, 0, 0);
                f32x4 w0 = *(const f32x4*)&hw[h][0];
                f32x4 w1 = *(const f32x4*)&hw[h][4];
                f32x4 w2 = *(const f32x4*)&hw[h][8];
                #pragma unroll
                for (int r = 0; r < 4; r++){
                    tv[r][0] += s[r] * w0;
                    tv[r][1] += s[r] * w1;
                    tv[r][2] += s[r] * w2;
                }
            }
            #pragma unroll
            for (int r = 0; r < 4; r++){
                const float adjv = adj[(size_t)(qt0 + quad*4 + r) * N_TOK + k0 + col];
                #pragma unroll
                for (int j = 0; j < 3; j++){
                    #pragma unroll
                    for (int c = 0; c < 4; c++){
                        const float mm = tv[r][j][c] * adjv;   // matches T*adj
                        if (mm != 0.f) l4[r][j][c] += __expf(mm);
                    }
                }
            }
        }
    }
    // reduce across the 16 k-columns (lanes within a quad), then atomicAdd
    #pragma unroll
    for (int r = 0; r < 4; r++)
        #pragma unroll
        for (int j = 0; j < 3; j++)
            #pragma unroll
            for (int c = 0; c < 4; c++){
                float v = l4[r][j][c];
                v += __shfl_xor(v, 1, 16);
                v += __shfl_xor(v, 2, 16);
                v += __shfl_xor(v, 4, 16);
                v += __shfl_xor(v, 8, 16);
                if (col == j*4 + c)
                    atomicAdd(&l_ws[(size_t)(qt0 + quad*4 + r) * NH + (j*4 + c)], v);
            }
}

// ---------------------------------------------------------------------------
// lse + energy:  lse = log(l) (or -1e30 marker), E += -(1/beta)*lse
// ---------------------------------------------------------------------------
__global__ __launch_bounds__(256) void lse_energy_kernel(
    const float* __restrict__ l_ws, float* __restrict__ lse_ws,
    const float* __restrict__ betas, float* __restrict__ energy)
{
    const int t = threadIdx.x;
    const int i = blockIdx.x * 256 + t;
    const float l = l_ws[i];
    float lse, ep;
    if (l > 0.f){ lse = logf(l); ep = -(1.f / betas[i % NH]) * lse; }
    else        { lse = -1e30f; ep = 0.f; }
    lse_ws[i] = lse;
    __shared__ float red[256];
    red[t] = ep;
    __syncthreads();
    for (int s = 128; s > 0; s >>= 1){
        if (t < s) red[t] += red[t + s];
        __syncthreads();
    }
    if (t == 0) atomicAdd(energy, red[0]);
}

// ---------------------------------------------------------------------------
// backward (symmetric two modes):
//  mode 0: rows = q-tile (rowmat=Qb), cols = k (colmat=Kh), out = dQb partials,
//          lse indexed by row.
//  mode 1: rows = k-tile (rowmat=Kh), cols = q (colmat=Qb), out = dKh partials,
//          lse indexed by col.
// Per 64-col chunk: phase A recomputes scores (bitwise-identical MFMA chain),
// P=exp(t-lse), G=-P/beta', dS = G @ Hw^T -> LDS (bf16, A-frag layout);
// phase B: MFMA outer product dRow[m][z] += dS[m][kk] * colmat[kk][z].
// ---------------------------------------------------------------------------
#define CBS 776   // colbuf ushort stride
#define DSS 72    // dsbuf ushort stride

__global__ __launch_bounds__(256, 1) void bwd_kernel(
    const unsigned short* __restrict__ rowmat, const unsigned short* __restrict__ colmat,
    const float* __restrict__ adj, const float* __restrict__ HwG,
    const float* __restrict__ lse_ws, const float* __restrict__ betas,
    float* __restrict__ out_part, int seg_len, int mode)
{
    __shared__ unsigned short colbuf[64][CBS];     // 99328 B
    __shared__ unsigned short dsbuf[NH][16][DSS];  // 27648 B
    __shared__ float adjbuf[16][68];               //  4352 B
    __shared__ float lsebuf[64 * NH];              //  3072 B
    __shared__ float hw[NH][12];                   //   576 B
    const int t = threadIdx.x;
    if (t < NH * 12) hw[t / 12][t % 12] = HwG[t];
    const int lane = t & 63, wave = t >> 6;
    const int quad = lane >> 4, col = lane & 15;
    const int rt0 = blockIdx.x * 16;
    const int cstart = blockIdx.y * seg_len;

    f32x4 invb[3];
    #pragma unroll
    for (int j = 0; j < 3; j++)
        #pragma unroll
        for (int c = 0; c < 4; c++) invb[j][c] = 1.f / betas[j*4 + c];

    bf16x8 af[NH][2];
    {
        const int arow = rt0 + col;
        #pragma unroll
        for (int h = 0; h < NH; h++)
            #pragma unroll
            for (int kk = 0; kk < 2; kk++)
                af[h][kk] = *(const bf16x8*)&rowmat[(size_t)arow * CDIM + h*HD + kk*32 + quad*8];
    }
    f32x4 lrow[4][3];
    if (mode == 0){
        #pragma unroll
        for (int r = 0; r < 4; r++)
            #pragma unroll
            for (int j = 0; j < 3; j++)
                lrow[r][j] = *(const f32x4*)&lse_ws[(size_t)(rt0 + quad*4 + r) * NH + j*4];
    }
    f32x4 accB[3][4];
    #pragma unroll
    for (int hh = 0; hh < 3; hh++)
        #pragma unroll
        for (int zt = 0; zt < 4; zt++)
            accB[hh][zt] = (f32x4){0.f,0.f,0.f,0.f};

    const int n0 = wave * 16;   // this wave's col sub-tile in phase A

    for (int cb = cstart; cb < cstart + seg_len; cb += 64){
        __syncthreads();
        #pragma unroll
        for (int i = 0; i < 24; i++){
            const int idx = t + 256 * i;
            const int row = idx / 96, cc = (idx % 96) * 8;
            *(bf16x8*)&colbuf[row][cc] = *(const bf16x8*)&colmat[(size_t)(cb + row) * CDIM + cc];
        }
        if (mode == 0){
            const int m = t >> 4, nc = (t & 15) * 4;
            f32x4 a = *(const f32x4*)&adj[(size_t)(rt0 + m) * N_TOK + cb + nc];
            adjbuf[m][nc+0] = a[0]; adjbuf[m][nc+1] = a[1];
            adjbuf[m][nc+2] = a[2]; adjbuf[m][nc+3] = a[3];
        } else {
            const int qr = t >> 2, kc = (t & 3) * 4;
            f32x4 a = *(const f32x4*)&adj[(size_t)(cb + qr) * N_TOK + rt0 + kc];
            adjbuf[kc+0][qr] = a[0]; adjbuf[kc+1][qr] = a[1];
            adjbuf[kc+2][qr] = a[2]; adjbuf[kc+3][qr] = a[3];
        }
        if (mode == 1 && t < 192)
            *(f32x4*)&lsebuf[t*4] = *(const f32x4*)&lse_ws[(size_t)cb * NH + t*4];
        __syncthreads();

        // ---- phase A ----
        {
            f32x4 G[4][3];
            #pragma unroll
            for (int r = 0; r < 4; r++)
                #pragma unroll
                for (int j = 0; j < 3; j++)
                    G[r][j] = (f32x4){0.f,0.f,0.f,0.f};
            #pragma unroll
            for (int h = 0; h < NH; h++){
                bf16x8 b0 = *(const bf16x8*)&colbuf[n0 + col][h*HD + quad*8];
                bf16x8 b1 = *(const bf16x8*)&colbuf[n0 + col][h*HD + 32 + quad*8];
                f32x4 s = {0.f,0.f,0.f,0.f};
                s = __builtin_amdgcn_mfma_f32_16x16x32_bf16(af[h][0], b0, s, 0, 0, 0);
                s = __builtin_amdgcn_mfma_f32_16x16x32_bf16(af[h][1], b1, s, 0, 0, 0);
                f32x4 w0 = *(const f32x4*)&hw[h][0];
                f32x4 w1 = *(const f32x4*)&hw[h][4];
                f32x4 w2 = *(const f32x4*)&hw[h][8];
                #pragma unroll
                for (int r = 0; r < 4; r++){
                    G[r][0] += s[r] * w0;
                    G[r][1] += s[r] * w1;
                    G[r][2] += s[r] * w2;
                }
            }
            // G currently holds t-values; convert to gradient G = -(1/b')*P
            #pragma unroll
            for (int r = 0; r < 4; r++){
                const float adjv = adjbuf[quad*4 + r][n0 + col];
                f32x4 lv0, lv1, lv2;
                if (mode == 0){ lv0 = lrow[r][0]; lv1 = lrow[r][1]; lv2 = lrow[r][2]; }
                else {
                    lv0 = *(const f32x4*)&lsebuf[(n0 + col) * NH + 0];
                    lv1 = *(const f32x4*)&lsebuf[(n0 + col) * NH + 4];
                    lv2 = *(const f32x4*)&lsebuf[(n0 + col) * NH + 8];
                }
                f32x4 lv[3] = { lv0, lv1, lv2 };
                #pragma unroll
                for (int j = 0; j < 3; j++)
                    #pragma unroll
                    for (int c = 0; c < 4; c++){
                        const float mm = G[r][j][c] * adjv;
                        const float p  = (mm != 0.f) ? __expf(mm - lv[j][c]) : 0.f;
                        G[r][j][c] = -invb[j][c] * p;
                    }
            }
            // dS = G @ Hw^T, write bf16 to LDS in A-operand layout
            #pragma unroll
            for (int h = 0; h < NH; h++){
                f32x4 w0 = *(const f32x4*)&hw[h][0];
                f32x4 w1 = *(const f32x4*)&hw[h][4];
                f32x4 w2 = *(const f32x4*)&hw[h][8];
                #pragma unroll
                for (int r = 0; r < 4; r++){
                    f32x4 pr = G[r][0]*w0 + G[r][1]*w1 + G[r][2]*w2;
                    const float d = pr[0] + pr[1] + pr[2] + pr[3];
                    dsbuf[h][quad*4 + r][n0 + col] = f2bf(d);
                }
            }
        }
        __syncthreads();

        // ---- phase B: dRow[m][z] += sum_kk dS[m][kk] * colmat[kk][z] ----
        #pragma unroll
        for (int hh = 0; hh < 3; hh++){
            const int h = wave + hh*4;
            #pragma unroll
            for (int ks = 0; ks < 2; ks++){
                bf16x8 a = *(const bf16x8*)&dsbuf[h][col][ks*32 + quad*8];
                #pragma unroll
                for (int zt = 0; zt < 4; zt++){
                    bf16x8 b;
                    #pragma unroll
                    for (int jj = 0; jj < 8; jj++)
                        b[jj] = (short)colbuf[ks*32 + quad*8 + jj][h*HD + zt*16 + col];
                    accB[hh][zt] = __builtin_amdgcn_mfma_f32_16x16x32_bf16(a, b, accB[hh][zt], 0, 0, 0);
                }
            }
        }
    }
    float* outp = out_part + (size_t)blockIdx.y * N_TOK * CDIM;
    #pragma unroll
    for (int hh = 0; hh < 3; hh++){
        const int h = wave + hh*4;
        #pragma unroll
        for (int zt = 0; zt < 4; zt++)
            #pragma unroll
            for (int r = 0; r < 4; r++)
                outp[(size_t)(rt0 + quad*4 + r) * CDIM + h*HD + zt*16 + col] = accB[hh][zt][r];
    }
}

// ---------------------------------------------------------------------------
// final: dg[n][d] = sum_c beta[c/64]*dQb[n][c]*Wq[c][d] + dKh[n][c]*Wk[c][d]
// (summing KS k-split partials at A-tile load)
// ---------------------------------------------------------------------------
__global__ __launch_bounds__(256) void final_dg_kernel(
    const float* __restrict__ dQbp, const float* __restrict__ dKhp,
    const float* __restrict__ Wq, const float* __restrict__ Wk,
    const float* __restrict__ betas, float* __restrict__ dg, int nseg)
{
    __shared__ float at[16][68];
    __shared__ float bt[16][68];
    const int n0 = blockIdx.x * 64, d0 = blockIdx.y * 64;
    const int t  = threadIdx.x;
    const int tx = t & 15, ty = t >> 4;
    const int lr = t >> 2, lk = (t & 3) * 4;
    float acc[4][4] = {};
    for (int src = 0; src < 2; src++){
        const float* P = src ? dKhp : dQbp;
        const float* W = src ? Wk  : Wq;
        for (int c0 = 0; c0 < CDIM; c0 += 16){
            __syncthreads();
            f32x4 a = {0.f,0.f,0.f,0.f};
            for (int s = 0; s < nseg; s++)
                a += *(const f32x4*)&P[((size_t)s * N_TOK + n0 + lr) * CDIM + c0 + lk];
            if (src == 0){
                const float bs = betas[(c0 + lk) >> 6];
                a *= bs;
            }
            at[lk+0][lr] = a[0]; at[lk+1][lr] = a[1]; at[lk+2][lr] = a[2]; at[lk+3][lr] = a[3];
            {
                const int kk = t >> 4, dd = (t & 15) * 4;
                f32x4 wv = *(const f32x4*)&W[(size_t)(c0 + kk) * DIM_IN + d0 + dd];
                bt[kk][dd+0] = wv[0]; bt[kk][dd+1] = wv[1]; bt[kk][dd+2] = wv[2]; bt[kk][dd+3] = wv[3];
            }
            __syncthreads();
            #pragma unroll
            for (int kk = 0; kk < 16; kk++){
                f32x4 av = *(const f32x4*)&at[kk][ty*4];
                f32x4 bv = *(const f32x4*)&bt[kk][tx*4];
                #pragma unroll
                for (int i = 0; i < 4; i++)
                    #pragma unroll
                    for (int j = 0; j < 4; j++)
                        acc[i][j] += av[i] * bv[j];
            }
        }
    }
    #pragma unroll
    for (int i = 0; i < 4; i++)
        #pragma unroll
        for (int j = 0; j < 4; j++)
            dg[(size_t)(n0 + ty*4 + i) * DIM_IN + d0 + tx*4 + j] = acc[i][j];
}

// ---------------------------------------------------------------------------
extern "C" void kernel_launch(void* const* d_in, const int* in_sizes, int n_in,
                              void* d_out, int out_size, void* d_ws, size_t ws_size,
                              hipStream_t stream)
{
    const float* g     = (const float*)d_in[0];
    const float* adj   = (const float*)d_in[1];
    const float* Wk    = (const float*)d_in[2];
    const float* Wq    = (const float*)d_in[3];
    const float* Hw    = (const float*)d_in[4];
    const float* Bk    = (const float*)d_in[5];
    const float* Bq    = (const float*)d_in[6];
    const float* betas = (const float*)d_in[7];
    float* out = (float*)d_out;

    char* ws = (char*)d_ws;
    const size_t szQb   = (size_t)N_TOK * CDIM * sizeof(unsigned short); // 6291456
    const size_t szL    = (size_t)N_TOK * NH * sizeof(float);            // 196608
    const size_t szPart = (size_t)N_TOK * CDIM * sizeof(float);          // 12582912

    unsigned short* Qb = (unsigned short*)(ws);
    unsigned short* Kh = (unsigned short*)(ws + szQb);
    float* l_ws   = (float*)(ws + 2*szQb);
    float* lse_ws = (float*)(ws + 2*szQb + szL);
    char*  parts  = ws + 2*szQb + 2*szL;
    const size_t base = 2*szQb + 2*szL;

    int KS = 1;
    if      (ws_size >= base + 8*szPart) KS = 4;
    else if (ws_size >= base + 4*szPart) KS = 2;
    float* dQbp = (float*)parts;
    float* dKhp = (float*)(parts + (size_t)KS * szPart);

    hipMemsetAsync(l_ws, 0, szL, stream);
    hipMemsetAsync(d_out, 0, sizeof(float), stream);

    proj_kernel<<<dim3(64, 12), 256, 0, stream>>>(g, Wq, Bq, betas, Qb);
    proj_kernel<<<dim3(64, 12), 256, 0, stream>>>(g, Wk, Bk, nullptr, Kh);
    fwd_kernel<<<dim3(64, 8), 256, 0, stream>>>(Qb, Kh, adj, Hw, l_ws, N_TOK / 8);
    lse_energy_kernel<<<dim3(192), 256, 0, stream>>>(l_ws, lse_ws, betas, out);
    bwd_kernel<<<dim3(256, KS), 256, 0, stream>>>(Qb, Kh, adj, Hw, lse_ws, betas,
                                                  dQbp, N_TOK / KS, 0);
    bwd_kernel<<<dim3(256, KS), 256, 0, stream>>>(Kh, Qb, adj, Hw, lse_ws, betas,
                                                  dKhp, N_TOK / KS, 1);
    final_dg_kernel<<<dim3(64, 8), 256, 0, stream>>>(dQbp, dKhp, Wq, Wk, betas,
                                                     out + 1, KS);
}